// Round 8
// baseline (193.647 us; speedup 1.0000x reference)
//
#include <hip/hip_runtime.h>
#include <hip/hip_bf16.h>

// Problem constants
#define Bq 2
#define Tq 2048
#define Cq 1024
#define Hq 16
#define HKVq 4
#define HDq 64
#define Gq 4
#define WSq 1024
#define GATE_CHq 32

typedef __attribute__((ext_vector_type(8))) short short8;   // 8 bf16 (4 VGPRs)
typedef __attribute__((ext_vector_type(4))) float f32x4;    // MFMA C/D frag
typedef __attribute__((ext_vector_type(2))) unsigned int u32x2;
typedef unsigned int u32;
typedef unsigned short u16;

#if __has_builtin(__builtin_amdgcn_exp2f)
#define EXP2(x) __builtin_amdgcn_exp2f(x)
#else
#define EXP2(x) exp2f(x)
#endif

__device__ __forceinline__ u16 f2bf(float f) {
  u32 u = __float_as_uint(f);
  u32 r = (u + 0x7FFFu + ((u >> 16) & 1u)) >> 16;  // RNE
  return (u16)r;
}
__device__ __forceinline__ float bf2f(u16 u) {
  return __uint_as_float(((u32)u) << 16);
}

__device__ __forceinline__ void gl_lds16(const u16* g, u16* l) {
  __builtin_amdgcn_global_load_lds(
      (const u32 __attribute__((address_space(1)))*)g,
      (u32 __attribute__((address_space(3)))*)l, 16, 0, 0);
}

// ---------------------------------------------------------------------------
// Fused QKV GEMM + RoPE/RMSNorm/gate epilogue (unchanged from round 7).
// ---------------------------------------------------------------------------
__global__ __launch_bounds__(256) void qkv_gemm_fused(
    const u16* __restrict__ A, const u16* __restrict__ Bt,
    const float* __restrict__ ve, const float* __restrict__ cosp,
    const float* __restrict__ sinp, const float* __restrict__ gatebuf,
    u16* __restrict__ Qb, u16* __restrict__ Kb, u16* __restrict__ Vtb) {
  __shared__ __attribute__((aligned(16))) u16 As[64 * 64];    // 8 KB
  __shared__ __attribute__((aligned(16))) u16 Bs[128 * 64];   // 16 KB

  const int bx = blockIdx.x;
  const int bm0 = blockIdx.y * 64, bn0 = bx * 128;
  const int tid = threadIdx.x;
  const int w = tid >> 6, lane = tid & 63;
  const int wm = (w >> 1) * 32, wn = (w & 1) * 64;
  const int quad = lane >> 4, l16 = lane & 15;
  const int K = 1024;

  f32x4 acc[2][4];
#pragma unroll
  for (int mt = 0; mt < 2; mt++)
#pragma unroll
    for (int nt = 0; nt < 4; nt++) acc[mt][nt] = (f32x4){0.f, 0.f, 0.f, 0.f};

  int goffA[2], goffB[4];
#pragma unroll
  for (int i = 0; i < 2; i++) {
    int s = i * 256 + tid;
    int m = s >> 3, gp = s & 7;
    goffA[i] = m * K + (gp ^ (m & 7)) * 8;
  }
#pragma unroll
  for (int i = 0; i < 4; i++) {
    int s = i * 256 + tid;
    int m = s >> 3, gp = s & 7;
    goffB[i] = m * K + (gp ^ (m & 7)) * 8;
  }
  const u16* Ab = A + (long)bm0 * K;
  const u16* Bb = Bt + (long)bn0 * K;

  for (int k0 = 0; k0 < K; k0 += 64) {
    __syncthreads();
#pragma unroll
    for (int i = 0; i < 2; i++)
      gl_lds16(Ab + goffA[i] + k0, &As[(i * 256 + w * 64) * 8]);
#pragma unroll
    for (int i = 0; i < 4; i++)
      gl_lds16(Bb + goffB[i] + k0, &Bs[(i * 256 + w * 64) * 8]);
    __syncthreads();

#pragma unroll
    for (int ks = 0; ks < 2; ks++) {
      short8 af[2], bf[4];
#pragma unroll
      for (int mt = 0; mt < 2; mt++) {
        int ml = wm + mt * 16 + l16;
        af[mt] = *(const short8*)&As[ml * 64 + (((ks * 4 + quad) ^ (ml & 7)) * 8)];
      }
#pragma unroll
      for (int nt = 0; nt < 4; nt++) {
        int nl = wn + nt * 16 + l16;
        bf[nt] = *(const short8*)&Bs[nl * 64 + (((ks * 4 + quad) ^ (nl & 7)) * 8)];
      }
#pragma unroll
      for (int mt = 0; mt < 2; mt++)
#pragma unroll
        for (int nt = 0; nt < 4; nt++)
          acc[mt][nt] = __builtin_amdgcn_mfma_f32_16x16x32_bf16(
              af[mt], bf[nt], acc[mt][nt], 0, 0, 0);
    }
  }

  // ---- fused epilogue ----
  const int b = bm0 >> 11;
  const int tseq0 = (bm0 & 2047) + wm;

  if (bx < 10) {
    u16* Dst;
    if (bx < 8) {
      int hh = bx * 2 + (w & 1);
      int hkv = hh >> 2, g = hh & 3;
      Dst = Qb + ((long)((b * 4 + hkv) * 4 + g) * Tq) * 64;
    } else {
      int kk = (bx - 8) * 2 + (w & 1);
      Dst = Kb + ((long)(b * 4 + kk) * Tq) * 64;
    }
#pragma unroll
    for (int mt = 0; mt < 2; mt++) {
#pragma unroll
      for (int r = 0; r < 4; r++) {
        int t = tseq0 + mt * 16 + quad * 4 + r;
        float c0 = cosp[t * 32 + l16];
        float s0 = sinp[t * 32 + l16];
        float c1 = cosp[t * 32 + 16 + l16];
        float s1 = sinp[t * 32 + 16 + l16];
        float a0 = acc[mt][0][r], a1 = acc[mt][1][r];
        float a2 = acc[mt][2][r], a3 = acc[mt][3][r];
        float rp0 = a0 * c0 + a2 * s0;
        float rp1 = a1 * c1 + a3 * s1;
        float rp2 = a2 * c0 - a0 * s0;
        float rp3 = a3 * c1 - a1 * s1;
        float ss = rp0 * rp0 + rp1 * rp1 + rp2 * rp2 + rp3 * rp3;
        ss += __shfl_xor(ss, 1);
        ss += __shfl_xor(ss, 2);
        ss += __shfl_xor(ss, 4);
        ss += __shfl_xor(ss, 8);
        float sc = rsqrtf(ss * (1.f / 64.f) + 1.1920928955078125e-07f);
        u16* drow = Dst + (long)t * 64;
        drow[l16] = f2bf(rp0 * sc);
        drow[16 + l16] = f2bf(rp1 * sc);
        drow[32 + l16] = f2bf(rp2 * sc);
        drow[48 + l16] = f2bf(rp3 * sc);
      }
    }
  } else {
    int kk = (bx - 10) * 2 + (w & 1);
    u16* Dst = Vtb + ((long)(b * 4 + kk) * 64) * Tq;
#pragma unroll
    for (int mt = 0; mt < 2; mt++) {
      float vals[4][4];
#pragma unroll
      for (int r = 0; r < 4; r++) {
        int t = tseq0 + mt * 16 + quad * 4 + r;
        long bt = (long)b * Tq + t;
        float gv = gatebuf[bt * 4 + kk];
        const float* verow = ve + bt * 256 + kk * 64;
#pragma unroll
        for (int nt = 0; nt < 4; nt++)
          vals[nt][r] = acc[mt][nt][r] + gv * verow[nt * 16 + l16];
      }
      int t0m = tseq0 + mt * 16 + quad * 4;
#pragma unroll
      for (int nt = 0; nt < 4; nt++) {
        int d = nt * 16 + l16;
        union { short4 v; u16 u[4]; } p;
#pragma unroll
        for (int r = 0; r < 4; r++) p.u[r] = f2bf(vals[nt][r]);
        *(short4*)(Dst + (long)d * Tq + t0m) = p.v;
      }
    }
  }
}

// ---------------------------------------------------------------------------
// proj GEMM (f32 out), 64x128 tile, BK=64 (unchanged).
// ---------------------------------------------------------------------------
__global__ __launch_bounds__(256) void gemm_proj(
    const u16* __restrict__ A, const u16* __restrict__ Bt,
    float* __restrict__ C, int M, int N, int K) {
  __shared__ __attribute__((aligned(16))) u16 As[64 * 64];
  __shared__ __attribute__((aligned(16))) u16 Bs[128 * 64];

  const int bm0 = blockIdx.y * 64, bn0 = blockIdx.x * 128;
  const int tid = threadIdx.x;
  const int w = tid >> 6, lane = tid & 63;
  const int wm = (w >> 1) * 32, wn = (w & 1) * 64;
  const int quad = lane >> 4, l16 = lane & 15;

  f32x4 acc[2][4];
#pragma unroll
  for (int mt = 0; mt < 2; mt++)
#pragma unroll
    for (int nt = 0; nt < 4; nt++) acc[mt][nt] = (f32x4){0.f, 0.f, 0.f, 0.f};

  int goffA[2], goffB[4];
#pragma unroll
  for (int i = 0; i < 2; i++) {
    int s = i * 256 + tid;
    int m = s >> 3, gp = s & 7;
    goffA[i] = m * K + (gp ^ (m & 7)) * 8;
  }
#pragma unroll
  for (int i = 0; i < 4; i++) {
    int s = i * 256 + tid;
    int m = s >> 3, gp = s & 7;
    goffB[i] = m * K + (gp ^ (m & 7)) * 8;
  }
  const u16* Ab = A + (long)bm0 * K;
  const u16* Bb = Bt + (long)bn0 * K;

  for (int k0 = 0; k0 < K; k0 += 64) {
    __syncthreads();
#pragma unroll
    for (int i = 0; i < 2; i++)
      gl_lds16(Ab + goffA[i] + k0, &As[(i * 256 + w * 64) * 8]);
#pragma unroll
    for (int i = 0; i < 4; i++)
      gl_lds16(Bb + goffB[i] + k0, &Bs[(i * 256 + w * 64) * 8]);
    __syncthreads();

#pragma unroll
    for (int ks = 0; ks < 2; ks++) {
      short8 af[2], bf[4];
#pragma unroll
      for (int mt = 0; mt < 2; mt++) {
        int ml = wm + mt * 16 + l16;
        af[mt] = *(const short8*)&As[ml * 64 + (((ks * 4 + quad) ^ (ml & 7)) * 8)];
      }
#pragma unroll
      for (int nt = 0; nt < 4; nt++) {
        int nl = wn + nt * 16 + l16;
        bf[nt] = *(const short8*)&Bs[nl * 64 + (((ks * 4 + quad) ^ (nl & 7)) * 8)];
      }
#pragma unroll
      for (int mt = 0; mt < 2; mt++)
#pragma unroll
        for (int nt = 0; nt < 4; nt++)
          acc[mt][nt] = __builtin_amdgcn_mfma_f32_16x16x32_bf16(
              af[mt], bf[nt], acc[mt][nt], 0, 0, 0);
    }
  }

#pragma unroll
  for (int mt = 0; mt < 2; mt++)
#pragma unroll
    for (int nt = 0; nt < 4; nt++) {
      int row0 = bm0 + wm + mt * 16 + quad * 4;
      int col = bn0 + wn + nt * 16 + l16;
#pragma unroll
      for (int r = 0; r < 4; r++)
        C[(long)(row0 + r) * N + col] = acc[mt][nt][r];
    }
}

// ---------------------------------------------------------------------------
// prep: x->bf16 + weight transposes + gate (unchanged).
// ---------------------------------------------------------------------------
__global__ __launch_bounds__(256) void prep(
    const float* __restrict__ x, u16* __restrict__ xb,
    const float* __restrict__ Wq, const float* __restrict__ Wk,
    const float* __restrict__ Wv, const float* __restrict__ Wproj,
    const float* __restrict__ Wg, u16* __restrict__ Dqkv,
    u16* __restrict__ Dproj, float* __restrict__ gatebuf) {
  __shared__ float tile[64][65];
  int bx = blockIdx.x;
  int tid = threadIdx.x;
  if (bx < 2048) {
    int i = (bx * 256 + tid) * 8;
    float4 a = *(const float4*)(x + i);
    float4 b = *(const float4*)(x + i + 4);
    union { short8 v; u16 u[8]; } o;
    o.u[0] = f2bf(a.x); o.u[1] = f2bf(a.y); o.u[2] = f2bf(a.z); o.u[3] = f2bf(a.w);
    o.u[4] = f2bf(b.x); o.u[5] = f2bf(b.y); o.u[6] = f2bf(b.z); o.u[7] = f2bf(b.w);
    *(short8*)(xb + i) = o.v;
    return;
  }
  if (bx >= 2688) {
    int p = (bx - 2688) * 256 + tid;   // 0..16383
    int bt = p >> 2, kk = p & 3;
    const float* xr = x + (long)bt * Cq;
    float dot = 0.f;
#pragma unroll
    for (int i = 0; i < GATE_CHq; i++) dot += xr[i] * Wg[i * HKVq + kk];
    gatebuf[p] = 2.f / (1.f + expf(-dot));
    return;
  }
  int wb = bx - 2048;
  int obx = wb >> 4;
  int k0 = (wb & 15) * 64;
  const float* S;
  u16* Dst;
  int N, nb;
  if (obx < 16)      { S = Wq;    N = 1024; nb = obx;      Dst = Dqkv; }
  else if (obx < 20) { S = Wk;    N = 256;  nb = obx - 16; Dst = Dqkv + 1024 * 1024; }
  else if (obx < 24) { S = Wv;    N = 256;  nb = obx - 20; Dst = Dqkv + 1280 * 1024; }
  else               { S = Wproj; N = 1024; nb = obx - 24; Dst = Dproj; }
  int n0 = nb * 64;
#pragma unroll
  for (int i = 0; i < 16; i++) {
    int idx = i * 256 + tid;
    int kl = idx >> 6, nl = idx & 63;
    tile[kl][nl] = S[(long)(k0 + kl) * N + n0 + nl];
  }
  __syncthreads();
#pragma unroll
  for (int i = 0; i < 16; i++) {
    int idx = i * 256 + tid;
    int nl = idx >> 6, kl = idx & 63;
    Dst[(long)(n0 + nl) * 1024 + k0 + kl] = f2bf(tile[kl][nl]);
  }
}

// ---------------------------------------------------------------------------
// MFMA flash attention v5: BARRIER-FREE K-loop.
// No K/V LDS staging — each wave loads K/V fragments directly from global
// (L1/L2-resident: XCD swizzle keeps one bh's 512 KB K+V on one XCD; all
// blocks on a CU share bh). P round-trip through wave-private LDS (lgkmcnt
// only, no __syncthreads anywhere in the loop). Fixed-max softmax.
// Block = (b,hkv,qt32), 512 blocks; 4 waves = 4 GQA heads.
// ---------------------------------------------------------------------------
#define CEXP 0.18033688011112042f   // 0.125 * log2(e)
#define CEXP8 1.4426950408889634f   // 8 * 0.125 * log2(e)

template <bool MASK>
__device__ __forceinline__ void attn_chunk(
    int k0, int q0, int quad, int l16, const u16* __restrict__ kf_addr,
    const u16* __restrict__ vf_addr, u32* __restrict__ myPs,
    const short8 (&QB)[2][2], f32x4 (&O)[2][4], float (&lsum)[2]) {
  // K-frags direct from global: A-operand (m=key=kt4*16+l16, k=d=quad*8+j)
  short8 kf[4][2];
#pragma unroll
  for (int kt4 = 0; kt4 < 4; kt4++) {
    kf[kt4][0] = *(const short8*)(kf_addr + kt4 * 1024);
    kf[kt4][1] = *(const short8*)(kf_addr + kt4 * 1024 + 32);
  }
  // V-frags direct from global: B-operand (n=d=nt*16+l16, k=key=quad*8+j)
  short8 vf[4][2];
#pragma unroll
  for (int nt = 0; nt < 4; nt++) {
    vf[nt][0] = *(const short8*)(vf_addr + (long)nt * 16 * Tq);
    vf[nt][1] = *(const short8*)(vf_addr + (long)nt * 16 * Tq + 32);
  }

  // S^T = K·Q^T
  f32x4 S4[4][2];
#pragma unroll
  for (int kt4 = 0; kt4 < 4; kt4++)
#pragma unroll
    for (int qj = 0; qj < 2; qj++) {
      f32x4 acc = (f32x4){0.f, 0.f, 0.f, 0.f};
      acc = __builtin_amdgcn_mfma_f32_16x16x32_bf16(kf[kt4][0], QB[qj][0], acc,
                                                    0, 0, 0);
      acc = __builtin_amdgcn_mfma_f32_16x16x32_bf16(kf[kt4][1], QB[qj][1], acc,
                                                    0, 0, 0);
      S4[kt4][qj] = acc;
    }

  // p = exp2(s*CEXP - CEXP8); pack bf16 pairs -> wave-private LDS
#pragma unroll
  for (int kt4 = 0; kt4 < 4; kt4++)
#pragma unroll
    for (int qj = 0; qj < 2; qj++) {
      float Pv[4];
#pragma unroll
      for (int r = 0; r < 4; r++) {
        float sv = S4[kt4][qj][r];
        if (MASK) {
          int kpos = k0 + kt4 * 16 + quad * 4 + r;
          int qpos = q0 + qj * 16 + l16;
          bool valid = (kpos <= qpos) && (kpos >= qpos - (WSq - 1));
          sv = valid ? sv : -1e30f;
        }
        float p = EXP2(__builtin_fmaf(sv, CEXP, -CEXP8));
        Pv[r] = p;
        lsum[qj] += p;
      }
      u32x2 pk;
#pragma unroll
      for (int rp = 0; rp < 2; rp++) {
        u32 lo = __float_as_uint(Pv[2 * rp]) + 0x8000u;
        u32 hi = __float_as_uint(Pv[2 * rp + 1]) + 0x8000u;
        pk[rp] = __builtin_amdgcn_perm(hi, lo, 0x07060302u);
      }
      *(u32x2*)(&myPs[(qj * 16 + l16) * 36 + kt4 * 8 + quad * 2]) = pk;
    }

  // O += P·V : A = P (m=q, k=key)
#pragma unroll
  for (int qj = 0; qj < 2; qj++) {
    const u32* prow = &myPs[(qj * 16 + l16) * 36];
    short8 pa0 = *(const short8*)(prow + quad * 4);
    short8 pa1 = *(const short8*)(prow + 16 + quad * 4);
#pragma unroll
    for (int nt = 0; nt < 4; nt++) {
      O[qj][nt] =
          __builtin_amdgcn_mfma_f32_16x16x32_bf16(pa0, vf[nt][0], O[qj][nt], 0, 0, 0);
      O[qj][nt] =
          __builtin_amdgcn_mfma_f32_16x16x32_bf16(pa1, vf[nt][1], O[qj][nt], 0, 0, 0);
    }
  }
}

__global__ __launch_bounds__(256, 3) void attn_mfma(
    const u16* __restrict__ Qb, const u16* __restrict__ Kb,
    const u16* __restrict__ Vtb, u16* __restrict__ Yb) {
  __shared__ __attribute__((aligned(16))) u32 Ps[4][32 * 36];  // 18.4 KB

  int bid = blockIdx.x;
  int bh = bid & 7;             // b*4+hkv -> same XCD L2 + same-CU L1 reuse
  int qt32 = bid >> 3;
  int hkv = bh & 3;
  int b = bh >> 2;
  int q0 = qt32 * 32;
  int tid = threadIdx.x;
  int g = tid >> 6;
  int lane = tid & 63;
  int quad = lane >> 4;
  int l16 = lane & 15;

  short8 QB[2][2];
#pragma unroll
  for (int qj = 0; qj < 2; qj++) {
    const u16* qb =
        Qb + ((long)((bh * 4 + g) * Tq + q0 + qj * 16 + l16)) * 64 + quad * 8;
    QB[qj][0] = *(const short8*)(qb);
    QB[qj][1] = *(const short8*)(qb + 32);
  }

  f32x4 O[2][4];
#pragma unroll
  for (int qj = 0; qj < 2; qj++)
#pragma unroll
    for (int nt = 0; nt < 4; nt++) O[qj][nt] = (f32x4){0.f, 0.f, 0.f, 0.f};
  float lsum[2] = {0.f, 0.f};

  int lo = q0 - (WSq - 1);
  int k0s = (lo < 0 ? 0 : lo) & ~63;   // first chunk
  int k0e = q0 & ~63;                  // last chunk (covers diagonal)

  const u16* Kbase = Kb + ((long)bh * Tq) * 64;
  const u16* Vbase = Vtb + ((long)bh * 64) * Tq;
  u32* myPs = &Ps[g][0];

  const u16* kf_addr = Kbase + (long)(k0s + l16) * 64 + quad * 8;
  const u16* vf_addr = Vbase + (long)l16 * Tq + k0s + quad * 8;

  int k0 = k0s;
  if (q0 >= WSq && k0 < k0e) {   // first chunk window-masked
    attn_chunk<true>(k0, q0, quad, l16, kf_addr, vf_addr, myPs, QB, O, lsum);
    k0 += 64;
    kf_addr += 64 * 64;
    vf_addr += 64;
  }
  for (; k0 < k0e; k0 += 64) {   // interior: no masking
    attn_chunk<false>(k0, q0, quad, l16, kf_addr, vf_addr, myPs, QB, O, lsum);
    kf_addr += 64 * 64;
    vf_addr += 64;
  }
  // last chunk: causal-masked
  attn_chunk<true>(k0, q0, quad, l16, kf_addr, vf_addr, myPs, QB, O, lsum);

  // reduce l across quads
#pragma unroll
  for (int qj = 0; qj < 2; qj++) {
    lsum[qj] += __shfl_xor(lsum[qj], 16);
    lsum[qj] += __shfl_xor(lsum[qj], 32);
  }

  int h = hkv * 4 + g;
#pragma unroll
  for (int qj = 0; qj < 2; qj++) {
    float invl[4];
#pragma unroll
    for (int r = 0; r < 4; r++) invl[r] = 1.f / __shfl(lsum[qj], quad * 4 + r);
#pragma unroll
    for (int nt = 0; nt < 4; nt++)
#pragma unroll
      for (int r = 0; r < 4; r++)
        Yb[((long)(b * Tq + q0 + qj * 16 + quad * 4 + r)) * 1024 + h * 64 +
           nt * 16 + l16] = f2bf(O[qj][nt][r] * invl[r]);
  }
}

// ---------------------------------------------------------------------------
extern "C" void kernel_launch(void* const* d_in, const int* in_sizes, int n_in,
                              void* d_out, int out_size, void* d_ws,
                              size_t ws_size, hipStream_t stream) {
  const float* x     = (const float*)d_in[0];
  const float* ve    = (const float*)d_in[1];
  const float* cosp  = (const float*)d_in[2];
  const float* sinp  = (const float*)d_in[3];
  const float* Wq    = (const float*)d_in[4];
  const float* Wk    = (const float*)d_in[5];
  const float* Wv    = (const float*)d_in[6];
  const float* Wproj = (const float*)d_in[7];
  const float* Wg    = (const float*)d_in[8];

  // workspace layout (~26.3 MB):
  //  [ 0        ,  8,388,608)  xb bf16     -> Yb bf16 (xb dead after qkv gemm)
  //  [ 8,388,608, 11,534,336)  WqkvT bf16
  //  [11,534,336, 13,631,488)  WprojT bf16
  //  [13,631,488, 22,020,096)  Qb bf16
  //  [22,020,096, 24,117,248)  Kb bf16
  //  [24,117,248, 26,214,400)  Vtb bf16
  //  [26,214,400, 26,279,936)  gate f32 [4096][4]
  char* base = (char*)d_ws;
  u16* xb      = (u16*)(base);
  u16* Yb      = xb;
  u16* WqkvT   = (u16*)(base + 8388608);
  u16* WprojT  = (u16*)(base + 11534336);
  u16* Qb      = (u16*)(base + 13631488);
  u16* Kb      = (u16*)(base + 22020096);
  u16* Vtb     = (u16*)(base + 24117248);
  float* gateb = (float*)(base + 26214400);
  float* out = (float*)d_out;

  prep<<<2752, 256, 0, stream>>>(x, xb, Wq, Wk, Wv, Wproj, Wg, WqkvT, WprojT,
                                 gateb);
  qkv_gemm_fused<<<dim3(12, 64), 256, 0, stream>>>(xb, WqkvT, ve, cosp, sinp,
                                                   gateb, Qb, Kb, Vtb);
  attn_mfma<<<512, 256, 0, stream>>>(Qb, Kb, Vtb, Yb);
  gemm_proj<<<dim3(8, 64), 256, 0, stream>>>(Yb, WprojT, out, 4096, 1024, 1024);
}